// Round 7
// baseline (127.156 us; speedup 1.0000x reference)
//
#include <hip/hip_runtime.h>

#define D_ 512
#define L_ 256
#define B_ 16
#define T_ 3072
#define MELS_ 80
#define R_ 4096          // B_*L_ unique token rows
#define CS_ 4104         // mel^T column stride (floats)

typedef __bf16 bf16x8 __attribute__((ext_vector_type(8)));
typedef float f32x4 __attribute__((ext_vector_type(4)));

__device__ __forceinline__ unsigned f2bf(float f) {
  union { float f; unsigned u; } x; x.f = f;
  return (x.u + 0x7FFFu + ((x.u >> 16) & 1u)) >> 16;   // RNE
}
__device__ __forceinline__ float bf2f(unsigned h) {
  union { unsigned u; float f; } x; x.u = h << 16;
  return x.f;
}

// dst[n][k] = bf16(src[k][n]) ; src is [512][N] f32, dst is [N][512] bf16
__device__ __forceinline__ void transw_dev(const float* __restrict__ src,
                                           unsigned short* __restrict__ dst,
                                           int N, int local, float* sh) {
  int kt = local & 7, nt = local >> 3;
  int k0 = kt * 64, n0 = nt * 64;
  int tid = threadIdx.x;
  int c = tid & 63, r4 = tid >> 6;
  for (int it = 0; it < 16; ++it) {
    int r = it * 4 + r4;
    int n = n0 + c;
    sh[r * 65 + c] = (n < N) ? src[(k0 + r) * N + n] : 0.f;
  }
  __syncthreads();
  for (int it = 0; it < 16; ++it) {
    int r = it * 4 + r4;
    int n = n0 + r;
    if (n < N) dst[n * D_ + k0 + c] = (unsigned short)f2bf(sh[c * 65 + r]);
  }
}

// cumsum(dur) + searchsorted(right) -> enc-row index per frame (R_ = invalid)
__device__ __forceinline__ void tok_dev(const int* __restrict__ dur,
                                        int* __restrict__ TOK, int b, int* cs) {
  int tid = threadIdx.x;
  cs[tid] = dur[b * L_ + tid];
  for (int off = 1; off < L_; off <<= 1) {
    __syncthreads();
    int v = (tid >= off) ? cs[tid - off] : 0;
    __syncthreads();
    cs[tid] += v;
  }
  __syncthreads();
  for (int t = tid; t < T_; t += 256) {
    int lo = 0, hi = L_;
    while (lo < hi) { int mid = (lo + hi) >> 1; if (cs[mid] <= t) lo = mid + 1; else hi = mid; }
    TOK[b * T_ + t] = (lo < L_) ? (b * L_ + lo) : R_;
  }
}

// ---- C = relu(A @ Bt^T + bias); 64x64 tile, BK=128 (4 barrier-drains) ----
// clampRow < 0: all 64 A-rows valid (no per-row min in staging).
__device__ __forceinline__ void gemm_tile(
    const unsigned short* __restrict__ A, const unsigned short* __restrict__ Bt,
    const float* __restrict__ bias, unsigned short* __restrict__ C,
    int m0, int n0, int clampRow, int mstore, short* lsA, short* lsB) {
  int tid = threadIdx.x;
  int lane = tid & 63, w = tid >> 6;
  int wm = w >> 1, wn = w & 1;
  int col = lane & 15, quad = lane >> 4;
  f32x4 acc[2][2] = {};
  for (int ks = 0; ks < 4; ++ks) {
    int k0 = ks * 128;
    __syncthreads();                                  // LDS reuse guard
    if (clampRow < 0) {
      for (int it = 0; it < 4; ++it) {
        int linear = it * 256 + tid;
        int row = linear >> 4, p = linear & 15;
        int seg = (p + row) & 15;                     // additive swizzle
        const unsigned short* ga = A + (size_t)(m0 + row) * D_ + k0 + seg * 8;
        const unsigned short* gb = Bt + (size_t)(n0 + row) * D_ + k0 + seg * 8;
        short* la = lsA + (size_t)(it * 256 + (tid & ~63)) * 8;  // wave-uniform base
        short* lb = lsB + (size_t)(it * 256 + (tid & ~63)) * 8;
        __builtin_amdgcn_global_load_lds((const __attribute__((address_space(1))) void*)ga,
                                         (__attribute__((address_space(3))) void*)la, 16, 0, 0);
        __builtin_amdgcn_global_load_lds((const __attribute__((address_space(1))) void*)gb,
                                         (__attribute__((address_space(3))) void*)lb, 16, 0, 0);
      }
    } else {
      for (int it = 0; it < 4; ++it) {
        int linear = it * 256 + tid;
        int row = linear >> 4, p = linear & 15;
        int seg = (p + row) & 15;
        const unsigned short* ga = A + (size_t)min(m0 + row, clampRow) * D_ + k0 + seg * 8;
        const unsigned short* gb = Bt + (size_t)(n0 + row) * D_ + k0 + seg * 8;
        short* la = lsA + (size_t)(it * 256 + (tid & ~63)) * 8;
        short* lb = lsB + (size_t)(it * 256 + (tid & ~63)) * 8;
        __builtin_amdgcn_global_load_lds((const __attribute__((address_space(1))) void*)ga,
                                         (__attribute__((address_space(3))) void*)la, 16, 0, 0);
        __builtin_amdgcn_global_load_lds((const __attribute__((address_space(1))) void*)gb,
                                         (__attribute__((address_space(3))) void*)lb, 16, 0, 0);
      }
    }
    __syncthreads();                                  // drains vmcnt(0)
    for (int kk = 0; kk < 4; ++kk) {
      int s = kk * 4 + quad;                          // chunk 0..15 within BK
      bf16x8 af[2], bfr[2];
      for (int mt = 0; mt < 2; ++mt) {
        int r = wm * 32 + mt * 16 + col;
        af[mt] = *(const bf16x8*)(lsA + (size_t)r * 128 + ((s - r) & 15) * 8);
      }
      for (int nt = 0; nt < 2; ++nt) {
        int r = wn * 32 + nt * 16 + col;
        bfr[nt] = *(const bf16x8*)(lsB + (size_t)r * 128 + ((s - r) & 15) * 8);
      }
      for (int mt = 0; mt < 2; ++mt)
        for (int nt = 0; nt < 2; ++nt)
          acc[mt][nt] = __builtin_amdgcn_mfma_f32_16x16x32_bf16(af[mt], bfr[nt], acc[mt][nt], 0, 0, 0);
    }
  }
  for (int nt = 0; nt < 2; ++nt) {
    int n = n0 + wn * 32 + nt * 16 + col;
    float bn = bias[n];
    for (int mt = 0; mt < 2; ++mt) {
      int mb = m0 + wm * 32 + mt * 16 + quad * 4;
      for (int i = 0; i < 4; ++i) {
        int m = mb + i;
        if (m < mstore) {
          float v = acc[mt][nt][i] + bn;
          v = v > 0.f ? v : 0.f;
          C[(size_t)m * D_ + n] = (unsigned short)f2bf(v);
        }
      }
    }
  }
}

// ---- L1: X = bf16(emb[src]+pos) (512 blks, 8 rows) + WET transpose ----
__global__ void prep1(const int* __restrict__ src, const float* __restrict__ emb,
                      const float* __restrict__ pos, const float* __restrict__ Wenc,
                      unsigned short* __restrict__ X, unsigned short* __restrict__ WET) {
  __shared__ float sh[64 * 65];
  int bid = blockIdx.x, tid = threadIdx.x;
  if (bid < 512) {
    int lane = tid & 63, w = tid >> 6;
    for (int u = 0; u < 2; ++u) {
      int row = bid * 8 + u * 4 + w;
      int s = src[row];
      int l = row & (L_ - 1);
      int d = lane * 8;
      const float4* ep = (const float4*)(emb + (size_t)s * D_ + d);
      const float4* pp = (const float4*)(pos + (size_t)l * D_ + d);
      float4 a0 = ep[0], a1 = ep[1];
      float4 b0 = pp[0], b1 = pp[1];
      uint4 o;
      o.x = f2bf(a0.x + b0.x) | (f2bf(a0.y + b0.y) << 16);
      o.y = f2bf(a0.z + b0.z) | (f2bf(a0.w + b0.w) << 16);
      o.z = f2bf(a1.x + b1.x) | (f2bf(a1.y + b1.y) << 16);
      o.w = f2bf(a1.z + b1.z) | (f2bf(a1.w + b1.w) << 16);
      *(uint4*)(X + (size_t)row * D_ + d) = o;
    }
  } else {
    transw_dev(Wenc, WET, 512, bid - 512, sh);
  }
}

// ---- L2: encoder GEMM (512 blks, m-major-in-lsb for XCD A-panel locality) ----
// ---- + WDT/WGT/TOK prep tails + ENC zero-row tail ----
__global__ __launch_bounds__(256, 4) void gemm_enc(
    const unsigned short* __restrict__ X, const unsigned short* __restrict__ WET,
    const float* __restrict__ benc, unsigned short* __restrict__ ENC,
    const float* __restrict__ Wdec, const float* __restrict__ Wgen,
    const int* __restrict__ dur,
    unsigned short* __restrict__ WDT, unsigned short* __restrict__ WGT,
    int* __restrict__ TOK) {
  __shared__ __align__(16) char smem[32768];
  int bid = blockIdx.x, tid = threadIdx.x;
  if (bid < 512) {
    // xcd = bid%8 = m-tile lsb: all 8 n-blocks of one m-panel share an XCD L2
    gemm_tile(X, WET, benc, ENC, (bid & 63) * 64, (bid >> 6) * 64, -1, R_,
              (short*)smem, (short*)(smem + 16384));
  } else if (bid < 576) {
    transw_dev(Wdec, WDT, 512, bid - 512, (float*)smem);
  } else if (bid < 592) {
    transw_dev(Wgen, WGT, MELS_, bid - 576, (float*)smem);
  } else if (bid < 608) {
    tok_dev(dur, TOK, bid - 592, (int*)smem);
  } else {                                            // ENC[R_] = 0
    if (tid < 64) {
      uint4 z = {0u, 0u, 0u, 0u};
      *(uint4*)(ENC + (size_t)R_ * D_ + (tid & 63) * 8) = z;
    }
  }
}

// ---- L3: decoder GEMM (520 blks) + duration head (256 tail blks) ----
__global__ __launch_bounds__(256, 4) void gemm_dec(
    const unsigned short* __restrict__ ENC, const unsigned short* __restrict__ WDT,
    const float* __restrict__ bdec, unsigned short* __restrict__ DEC,
    const float* __restrict__ wdur, const float* __restrict__ bdur,
    float* __restrict__ durout) {
  __shared__ __align__(16) char smem[32768];
  int bid = blockIdx.x, tid = threadIdx.x;
  int lane = tid & 63, w = tid >> 6;
  if (bid >= 520) {                                   // duration head: 16 rows/block
    int b2 = bid - 520;
    float4 w0 = *(const float4*)(wdur + lane * 8);
    float4 w1 = *(const float4*)(wdur + lane * 8 + 4);
    float bv = bdur[0];
    for (int rep = 0; rep < 4; ++rep) {
      int row = b2 * 16 + w * 4 + rep;
      const uint4 e = *(const uint4*)(ENC + (size_t)row * D_ + lane * 8);
      float s = 0.f;
      s += bf2f(e.x & 0xffffu) * w0.x;  s += bf2f(e.x >> 16) * w0.y;
      s += bf2f(e.y & 0xffffu) * w0.z;  s += bf2f(e.y >> 16) * w0.w;
      s += bf2f(e.z & 0xffffu) * w1.x;  s += bf2f(e.z >> 16) * w1.y;
      s += bf2f(e.w & 0xffffu) * w1.z;  s += bf2f(e.w >> 16) * w1.w;
      for (int off = 32; off > 0; off >>= 1) s += __shfl_down(s, off, 64);
      if (lane == 0) durout[row] = s + bv;
    }
    return;
  }
  int m0, n0, clampRow;
  if (bid < 512) { m0 = (bid & 63) * 64; n0 = (bid >> 6) * 64; clampRow = -1; }
  else           { m0 = 4096;            n0 = (bid - 512) * 64; clampRow = R_; }
  gemm_tile(ENC, WDT, bdec, DEC, m0, n0, clampRow, R_ + 1,
            (short*)smem, (short*)(smem + 16384));
}

// ---- L4: mel^T[m][r] = dec[r]·W_gen[:,m] + b_gen[m] ; K split over 4 waves ----
__global__ void genk(const unsigned short* __restrict__ dec, const unsigned short* __restrict__ wgT,
                     const float* __restrict__ bgen, float* __restrict__ melT) {
  __shared__ float sh[4 * 80 * 16];
  int tid = threadIdx.x;
  int lane = tid & 63, w = tid >> 6;
  int col = lane & 15, quad = lane >> 4;
  int n0 = blockIdx.x * 16;
  int n = n0 + col;
  int nc = min(n, R_);
  f32x4 acc[5] = {};
  const unsigned short* dp = dec + (size_t)nc * D_ + quad * 8;
  for (int ks = 0; ks < 4; ++ks) {
    int k0 = (w * 4 + ks) * 32;
    bf16x8 bfr = *(const bf16x8*)(dp + k0);
    for (int mt = 0; mt < 5; ++mt) {
      bf16x8 afr = *(const bf16x8*)(wgT + (size_t)(mt * 16 + col) * D_ + k0 + quad * 8);
      acc[mt] = __builtin_amdgcn_mfma_f32_16x16x32_bf16(afr, bfr, acc[mt], 0, 0, 0);
    }
  }
  for (int mt = 0; mt < 5; ++mt)
    for (int i = 0; i < 4; ++i)
      sh[w * 1280 + (mt * 16 + quad * 4 + i) * 16 + col] = acc[mt][i];
  __syncthreads();
  for (int j = 0; j < 5; ++j) {
    int idx = j * 256 + tid;
    float v = sh[idx] + sh[1280 + idx] + sh[2560 + idx] + sh[3840 + idx];
    int m = idx >> 4;
    int nn = n0 + (idx & 15);
    if (nn <= R_) melT[(size_t)m * CS_ + nn] = v + bgen[m];
  }
}

// ---- L5: out[b][m][t] = mel^T[m][tok[b][t]] ; float4 coalesced stores ----
__global__ void outk(const int* __restrict__ TOK, const float* __restrict__ melT,
                     float* __restrict__ out) {
  int b = blockIdx.y;
  int tl = blockIdx.x * 128 + (threadIdx.x & 31) * 4;
  int m0 = threadIdx.x >> 5;
  int4 tg = *(const int4*)(TOK + b * T_ + tl);
  float* ob = out + (size_t)b * MELS_ * T_ + tl;
  for (int it = 0; it < 10; ++it) {
    int m = m0 + it * 8;
    const float* mr = melT + (size_t)m * CS_;
    float4 v = make_float4(mr[tg.x], mr[tg.y], mr[tg.z], mr[tg.w]);
    *(float4*)(ob + (size_t)m * T_) = v;
  }
}

extern "C" void kernel_launch(void* const* d_in, const int* in_sizes, int n_in,
                              void* d_out, int out_size, void* d_ws, size_t ws_size,
                              hipStream_t stream) {
  const int* src = (const int*)d_in[0];
  const int* dur = (const int*)d_in[1];
  const float* emb = (const float*)d_in[3];
  const float* pos = (const float*)d_in[4];
  const float* Wenc = (const float*)d_in[5];
  const float* benc = (const float*)d_in[6];
  const float* Wdur = (const float*)d_in[7];
  const float* bdur = (const float*)d_in[8];
  const float* Wdec = (const float*)d_in[9];
  const float* bdec = (const float*)d_in[10];
  const float* Wgen = (const float*)d_in[11];
  const float* bgen = (const float*)d_in[12];

  char* ws = (char*)d_ws;
  unsigned short* X   = (unsigned short*)(ws + 0);          // 4096x512 bf16
  unsigned short* ENC = (unsigned short*)(ws + 4194304);    // 4097x512 bf16 (row 4096 = 0)
  unsigned short* DEC = (unsigned short*)(ws + 8389632);    // 4097x512 bf16
  unsigned short* WET = (unsigned short*)(ws + 12584960);   // W_enc^T 512x512 bf16
  unsigned short* WDT = (unsigned short*)(ws + 13109248);   // W_dec^T 512x512 bf16
  unsigned short* WGT = (unsigned short*)(ws + 13633536);   // W_gen^T 80x512 bf16
  int* TOK            = (int*)(ws + 13715456);              // 16x3072 int
  float* MELT         = (float*)(ws + 13912064);            // 80x4104 f32

  float* out = (float*)d_out;
  float* durout = out + (size_t)B_ * MELS_ * T_;            // 3,932,160

  prep1<<<576, 256, 0, stream>>>(src, emb, pos, Wenc, X, WET);
  gemm_enc<<<609, 256, 0, stream>>>(X, WET, benc, ENC, Wdec, Wgen, dur, WDT, WGT, TOK);
  gemm_dec<<<776, 256, 0, stream>>>(ENC, WDT, bdec, DEC, Wdur, bdur, durout);
  genk<<<257, 256, 0, stream>>>(DEC, WGT, bgen, MELT);
  outk<<<dim3(24, 16), 256, 0, stream>>>(TOK, MELT, out);
}

// Round 8
// 121.656 us; speedup vs baseline: 1.0452x; 1.0452x over previous
//
#include <hip/hip_runtime.h>

#define D_ 512
#define L_ 256
#define B_ 16
#define T_ 3072
#define MELS_ 80
#define R_ 4096          // B_*L_ unique token rows
#define CS_ 4104         // mel^T column stride (floats)

typedef __bf16 bf16x8 __attribute__((ext_vector_type(8)));
typedef float f32x4 __attribute__((ext_vector_type(4)));

__device__ __forceinline__ unsigned f2bf(float f) {
  union { float f; unsigned u; } x; x.f = f;
  return (x.u + 0x7FFFu + ((x.u >> 16) & 1u)) >> 16;   // RNE
}
__device__ __forceinline__ float bf2f(unsigned h) {
  union { unsigned u; float f; } x; x.u = h << 16;
  return x.f;
}

// dst[n][k] = bf16(src[k][n]) ; src is [512][N] f32, dst is [N][512] bf16
__device__ __forceinline__ void transw_dev(const float* __restrict__ src,
                                           unsigned short* __restrict__ dst,
                                           int N, int local, float* sh) {
  int kt = local & 7, nt = local >> 3;
  int k0 = kt * 64, n0 = nt * 64;
  int tid = threadIdx.x;
  int c = tid & 63, r4 = tid >> 6;
  for (int it = 0; it < 16; ++it) {
    int r = it * 4 + r4;
    int n = n0 + c;
    sh[r * 65 + c] = (n < N) ? src[(k0 + r) * N + n] : 0.f;
  }
  __syncthreads();
  for (int it = 0; it < 16; ++it) {
    int r = it * 4 + r4;
    int n = n0 + r;
    if (n < N) dst[n * D_ + k0 + c] = (unsigned short)f2bf(sh[c * 65 + r]);
  }
}

// cumsum(dur) + searchsorted(right) -> enc-row index per frame (R_ = invalid)
__device__ __forceinline__ void tok_dev(const int* __restrict__ dur,
                                        int* __restrict__ TOK, int b, int* cs) {
  int tid = threadIdx.x;
  cs[tid] = dur[b * L_ + tid];
  for (int off = 1; off < L_; off <<= 1) {
    __syncthreads();
    int v = (tid >= off) ? cs[tid - off] : 0;
    __syncthreads();
    cs[tid] += v;
  }
  __syncthreads();
  for (int t = tid; t < T_; t += 256) {
    int lo = 0, hi = L_;
    while (lo < hi) { int mid = (lo + hi) >> 1; if (cs[mid] <= t) lo = mid + 1; else hi = mid; }
    TOK[b * T_ + t] = (lo < L_) ? (b * L_ + lo) : R_;
  }
}

// ---- C = relu(A @ Bt^T + bias); 64x64 tile, BK=128 (4 barrier-drains) ----
__device__ __forceinline__ void gemm_tile(
    const unsigned short* __restrict__ A, const unsigned short* __restrict__ Bt,
    const float* __restrict__ bias, unsigned short* __restrict__ C,
    int m0, int n0, int mclamp, int mstore, short* lsA, short* lsB) {
  int tid = threadIdx.x;
  int lane = tid & 63, w = tid >> 6;
  int wm = w >> 1, wn = w & 1;
  int col = lane & 15, quad = lane >> 4;
  f32x4 acc[2][2] = {};
  for (int ks = 0; ks < 4; ++ks) {
    int k0 = ks * 128;
    __syncthreads();                                  // LDS reuse guard
    for (int it = 0; it < 4; ++it) {
      int linear = it * 256 + tid;
      int row = linear >> 4, p = linear & 15;
      int seg = (p + row) & 15;                       // additive swizzle
      const unsigned short* ga = A + (size_t)min(m0 + row, mclamp) * D_ + k0 + seg * 8;
      const unsigned short* gb = Bt + (size_t)(n0 + row) * D_ + k0 + seg * 8;
      short* la = lsA + (size_t)(it * 256 + (tid & ~63)) * 8;  // wave-uniform base
      short* lb = lsB + (size_t)(it * 256 + (tid & ~63)) * 8;
      __builtin_amdgcn_global_load_lds((const __attribute__((address_space(1))) void*)ga,
                                       (__attribute__((address_space(3))) void*)la, 16, 0, 0);
      __builtin_amdgcn_global_load_lds((const __attribute__((address_space(1))) void*)gb,
                                       (__attribute__((address_space(3))) void*)lb, 16, 0, 0);
    }
    __syncthreads();                                  // drains vmcnt(0)
    for (int kk = 0; kk < 4; ++kk) {
      int s = kk * 4 + quad;                          // chunk 0..15 within BK
      bf16x8 af[2], bfr[2];
      for (int mt = 0; mt < 2; ++mt) {
        int r = wm * 32 + mt * 16 + col;
        af[mt] = *(const bf16x8*)(lsA + (size_t)r * 128 + ((s - r) & 15) * 8);
      }
      for (int nt = 0; nt < 2; ++nt) {
        int r = wn * 32 + nt * 16 + col;
        bfr[nt] = *(const bf16x8*)(lsB + (size_t)r * 128 + ((s - r) & 15) * 8);
      }
      for (int mt = 0; mt < 2; ++mt)
        for (int nt = 0; nt < 2; ++nt)
          acc[mt][nt] = __builtin_amdgcn_mfma_f32_16x16x32_bf16(af[mt], bfr[nt], acc[mt][nt], 0, 0, 0);
    }
  }
  for (int nt = 0; nt < 2; ++nt) {
    int n = n0 + wn * 32 + nt * 16 + col;
    float bn = bias[n];
    for (int mt = 0; mt < 2; ++mt) {
      int mb = m0 + wm * 32 + mt * 16 + quad * 4;
      for (int i = 0; i < 4; ++i) {
        int m = mb + i;
        if (m < mstore) {
          float v = acc[mt][nt][i] + bn;
          v = v > 0.f ? v : 0.f;
          C[(size_t)m * D_ + n] = (unsigned short)f2bf(v);
        }
      }
    }
  }
}

// ---- L1: X = bf16(emb[src]+pos) (512 blks, 8 rows) + WET transpose + ENC zero ----
__global__ void prep1(const int* __restrict__ src, const float* __restrict__ emb,
                      const float* __restrict__ pos, const float* __restrict__ Wenc,
                      unsigned short* __restrict__ X, unsigned short* __restrict__ WET,
                      unsigned short* __restrict__ ENC) {
  __shared__ float sh[64 * 65];
  int bid = blockIdx.x, tid = threadIdx.x;
  if (bid < 512) {
    int lane = tid & 63, w = tid >> 6;
    for (int u = 0; u < 2; ++u) {
      int row = bid * 8 + u * 4 + w;
      int s = src[row];
      int l = row & (L_ - 1);
      int d = lane * 8;
      const float4* ep = (const float4*)(emb + (size_t)s * D_ + d);
      const float4* pp = (const float4*)(pos + (size_t)l * D_ + d);
      float4 a0 = ep[0], a1 = ep[1];
      float4 b0 = pp[0], b1 = pp[1];
      uint4 o;
      o.x = f2bf(a0.x + b0.x) | (f2bf(a0.y + b0.y) << 16);
      o.y = f2bf(a0.z + b0.z) | (f2bf(a0.w + b0.w) << 16);
      o.z = f2bf(a1.x + b1.x) | (f2bf(a1.y + b1.y) << 16);
      o.w = f2bf(a1.z + b1.z) | (f2bf(a1.w + b1.w) << 16);
      *(uint4*)(X + (size_t)row * D_ + d) = o;
    }
  } else if (bid < 576) {
    transw_dev(Wenc, WET, 512, bid - 512, sh);
  } else {
    if (tid < 64) {
      uint4 z = {0u, 0u, 0u, 0u};
      *(uint4*)(ENC + (size_t)R_ * D_ + (tid & 63) * 8) = z;
    }
  }
}

// ---- L2: encoder GEMM (512 blks) + WDT/WGT/TOK prep tails ----
__global__ __launch_bounds__(256, 4) void gemm_enc(
    const unsigned short* __restrict__ X, const unsigned short* __restrict__ WET,
    const float* __restrict__ benc, unsigned short* __restrict__ ENC,
    const float* __restrict__ Wdec, const float* __restrict__ Wgen,
    const int* __restrict__ dur,
    unsigned short* __restrict__ WDT, unsigned short* __restrict__ WGT,
    int* __restrict__ TOK) {
  __shared__ __align__(16) char smem[32768];
  int bid = blockIdx.x;
  if (bid < 512) {
    // n-tile in lsb: each B-panel (the 64x-reused operand) stays XCD-local
    gemm_tile(X, WET, benc, ENC, (bid >> 3) * 64, (bid & 7) * 64, R_ - 1, R_,
              (short*)smem, (short*)(smem + 16384));
  } else if (bid < 576) {
    transw_dev(Wdec, WDT, 512, bid - 512, (float*)smem);
  } else if (bid < 592) {
    transw_dev(Wgen, WGT, MELS_, bid - 576, (float*)smem);
  } else {
    tok_dev(dur, TOK, bid - 592, (int*)smem);
  }
}

// ---- L3: decoder GEMM (520 blks) + duration head (256 tail blks) ----
__global__ __launch_bounds__(256, 4) void gemm_dec(
    const unsigned short* __restrict__ ENC, const unsigned short* __restrict__ WDT,
    const float* __restrict__ bdec, unsigned short* __restrict__ DEC,
    const float* __restrict__ wdur, const float* __restrict__ bdur,
    float* __restrict__ durout) {
  __shared__ __align__(16) char smem[32768];
  int bid = blockIdx.x, tid = threadIdx.x;
  int lane = tid & 63, w = tid >> 6;
  if (bid >= 520) {                                   // duration head: 16 rows/block
    int b2 = bid - 520;
    float4 w0 = *(const float4*)(wdur + lane * 8);
    float4 w1 = *(const float4*)(wdur + lane * 8 + 4);
    float bv = bdur[0];
    for (int rep = 0; rep < 4; ++rep) {
      int row = b2 * 16 + w * 4 + rep;
      const uint4 e = *(const uint4*)(ENC + (size_t)row * D_ + lane * 8);
      float s = 0.f;
      s += bf2f(e.x & 0xffffu) * w0.x;  s += bf2f(e.x >> 16) * w0.y;
      s += bf2f(e.y & 0xffffu) * w0.z;  s += bf2f(e.y >> 16) * w0.w;
      s += bf2f(e.z & 0xffffu) * w1.x;  s += bf2f(e.z >> 16) * w1.y;
      s += bf2f(e.w & 0xffffu) * w1.z;  s += bf2f(e.w >> 16) * w1.w;
      for (int off = 32; off > 0; off >>= 1) s += __shfl_down(s, off, 64);
      if (lane == 0) durout[row] = s + bv;
    }
    return;
  }
  gemm_tile(ENC, WDT, bdec, DEC, (bid >> 3) * 64, (bid & 7) * 64, R_, R_ + 1,
            (short*)smem, (short*)(smem + 16384));
}

// ---- L4: mel^T[m][r] = dec[r]·W_gen[:,m] + b_gen[m] ; K split over 4 waves ----
__global__ void genk(const unsigned short* __restrict__ dec, const unsigned short* __restrict__ wgT,
                     const float* __restrict__ bgen, float* __restrict__ melT) {
  __shared__ float sh[4 * 80 * 16];
  int tid = threadIdx.x;
  int lane = tid & 63, w = tid >> 6;
  int col = lane & 15, quad = lane >> 4;
  int n0 = blockIdx.x * 16;
  int n = n0 + col;
  int nc = min(n, R_);
  f32x4 acc[5] = {};
  const unsigned short* dp = dec + (size_t)nc * D_ + quad * 8;
  for (int ks = 0; ks < 4; ++ks) {
    int k0 = (w * 4 + ks) * 32;
    bf16x8 bfr = *(const bf16x8*)(dp + k0);
    for (int mt = 0; mt < 5; ++mt) {
      bf16x8 afr = *(const bf16x8*)(wgT + (size_t)(mt * 16 + col) * D_ + k0 + quad * 8);
      acc[mt] = __builtin_amdgcn_mfma_f32_16x16x32_bf16(afr, bfr, acc[mt], 0, 0, 0);
    }
  }
  for (int mt = 0; mt < 5; ++mt)
    for (int i = 0; i < 4; ++i)
      sh[w * 1280 + (mt * 16 + quad * 4 + i) * 16 + col] = acc[mt][i];
  __syncthreads();
  for (int j = 0; j < 5; ++j) {
    int idx = j * 256 + tid;
    float v = sh[idx] + sh[1280 + idx] + sh[2560 + idx] + sh[3840 + idx];
    int m = idx >> 4;
    int nn = n0 + (idx & 15);
    if (nn <= R_) melT[(size_t)m * CS_ + nn] = v + bgen[m];
  }
}

// ---- L5: out[b][m][t] = mel^T[m][tok[b][t]] ; float4 coalesced stores ----
__global__ void outk(const int* __restrict__ TOK, const float* __restrict__ melT,
                     float* __restrict__ out) {
  int b = blockIdx.y;
  int tl = blockIdx.x * 128 + (threadIdx.x & 31) * 4;
  int m0 = threadIdx.x >> 5;
  int4 tg = *(const int4*)(TOK + b * T_ + tl);
  float* ob = out + (size_t)b * MELS_ * T_ + tl;
  for (int it = 0; it < 10; ++it) {
    int m = m0 + it * 8;
    const float* mr = melT + (size_t)m * CS_;
    float4 v = make_float4(mr[tg.x], mr[tg.y], mr[tg.z], mr[tg.w]);
    *(float4*)(ob + (size_t)m * T_) = v;
  }
}

extern "C" void kernel_launch(void* const* d_in, const int* in_sizes, int n_in,
                              void* d_out, int out_size, void* d_ws, size_t ws_size,
                              hipStream_t stream) {
  const int* src = (const int*)d_in[0];
  const int* dur = (const int*)d_in[1];
  const float* emb = (const float*)d_in[3];
  const float* pos = (const float*)d_in[4];
  const float* Wenc = (const float*)d_in[5];
  const float* benc = (const float*)d_in[6];
  const float* Wdur = (const float*)d_in[7];
  const float* bdur = (const float*)d_in[8];
  const float* Wdec = (const float*)d_in[9];
  const float* bdec = (const float*)d_in[10];
  const float* Wgen = (const float*)d_in[11];
  const float* bgen = (const float*)d_in[12];

  char* ws = (char*)d_ws;
  unsigned short* X   = (unsigned short*)(ws + 0);          // 4096x512 bf16
  unsigned short* ENC = (unsigned short*)(ws + 4194304);    // 4097x512 bf16 (row 4096 = 0)
  unsigned short* DEC = (unsigned short*)(ws + 8389632);    // 4097x512 bf16
  unsigned short* WET = (unsigned short*)(ws + 12584960);   // W_enc^T 512x512 bf16
  unsigned short* WDT = (unsigned short*)(ws + 13109248);   // W_dec^T 512x512 bf16
  unsigned short* WGT = (unsigned short*)(ws + 13633536);   // W_gen^T 80x512 bf16
  int* TOK            = (int*)(ws + 13715456);              // 16x3072 int
  float* MELT         = (float*)(ws + 13912064);            // 80x4104 f32

  float* out = (float*)d_out;
  float* durout = out + (size_t)B_ * MELS_ * T_;            // 3,932,160

  prep1<<<577, 256, 0, stream>>>(src, emb, pos, Wenc, X, WET, ENC);
  gemm_enc<<<608, 256, 0, stream>>>(X, WET, benc, ENC, Wdec, Wgen, dur, WDT, WGT, TOK);
  gemm_dec<<<776, 256, 0, stream>>>(ENC, WDT, bdec, DEC, Wdur, bdur, durout);
  genk<<<257, 256, 0, stream>>>(DEC, WGT, bgen, MELT);
  outk<<<dim3(24, 16), 256, 0, stream>>>(TOK, MELT, out);
}